// Round 1
// baseline (39.950 us; speedup 1.0000x reference)
//
#include <hip/hip_runtime.h>

// Problem constants (from reference)
constexpr int NC = 2;   // N_CLASSES
constexpr int NF = 10;  // N_FEATURES
constexpr int PD = 10;  // PSI_DIM

// Kernel 1: compute M_r[k][a] = sum_{i,j} (pr_i*Ar[k,i,j,a] - pi_i*Ai[k,i,j,a]) * (pr_j - pi_j)
// Derivation: M_r = mat(pr,Ar,pr) - mat(pi,Ai,pr) - mat(pr,Ar,pi) + mat(pi,Ai,pi)
//           = sum_ij [ pr_i Ar (pr_j - pi_j) - pi_i Ai (pr_j - pi_j) ]
// (x_imag == 0 in the reference, so M_i never contributes to the output.)
__global__ void compute_M_kernel(const float* __restrict__ psi_r,
                                 const float* __restrict__ psi_i,
                                 const float* __restrict__ A_r,
                                 const float* __restrict__ A_i,
                                 float* __restrict__ M) {
    int t = threadIdx.x;
    if (t >= NC * NF) return;
    int k = t / NF;
    int a = t - k * NF;
    float acc = 0.f;
    for (int i = 0; i < PD; ++i) {
        float pri = psi_r[i];
        float pii = psi_i[i];
        for (int j = 0; j < PD; ++j) {
            float dj = psi_r[j] - psi_i[j];
            int idx = ((k * PD + i) * PD + j) * NF + a;
            acc = fmaf(pri * A_r[idx] - pii * A_i[idx], dj, acc);
        }
    }
    M[t] = acc;
}

// Kernel 2: out[t,k] = sum_a x[t,a] * M[k,a]; each thread does 2 rows so that
// loads are 5 aligned float4 (80 B per thread, 16B-aligned since 80 % 16 == 0)
// and the store is one float4 (out rows 2t,2t+1 are 4 contiguous floats).
__global__ __launch_bounds__(256) void apply_M_kernel(
        const float* __restrict__ x, const float* __restrict__ M,
        float* __restrict__ out, int T2) {
    float m0[NF], m1[NF];
#pragma unroll
    for (int a = 0; a < NF; ++a) {
        m0[a] = M[a];
        m1[a] = M[NF + a];
    }
    const int stride = gridDim.x * blockDim.x;
    for (int idx = blockIdx.x * blockDim.x + threadIdx.x; idx < T2; idx += stride) {
        const float4* xp = reinterpret_cast<const float4*>(x + (size_t)idx * 2 * NF);
        float4 v0 = xp[0];
        float4 v1 = xp[1];
        float4 v2 = xp[2];
        float4 v3 = xp[3];
        float4 v4 = xp[4];
        float r0[NF] = {v0.x, v0.y, v0.z, v0.w, v1.x, v1.y, v1.z, v1.w, v2.x, v2.y};
        float r1[NF] = {v2.z, v2.w, v3.x, v3.y, v3.z, v3.w, v4.x, v4.y, v4.z, v4.w};
        float4 o = {0.f, 0.f, 0.f, 0.f};
#pragma unroll
        for (int a = 0; a < NF; ++a) {
            o.x = fmaf(r0[a], m0[a], o.x);
            o.y = fmaf(r0[a], m1[a], o.y);
            o.z = fmaf(r1[a], m0[a], o.z);
            o.w = fmaf(r1[a], m1[a], o.w);
        }
        reinterpret_cast<float4*>(out)[idx] = o;
    }
}

extern "C" void kernel_launch(void* const* d_in, const int* in_sizes, int n_in,
                              void* d_out, int out_size, void* d_ws, size_t ws_size,
                              hipStream_t stream) {
    const float* x     = (const float*)d_in[0];
    const float* psi_r = (const float*)d_in[1];
    const float* psi_i = (const float*)d_in[2];
    const float* A_r   = (const float*)d_in[3];
    const float* A_i   = (const float*)d_in[4];
    float* out = (float*)d_out;
    float* M   = (float*)d_ws;  // 20 floats

    const int T  = in_sizes[0] / NF;  // 4,000,000
    const int T2 = T / 2;             // each thread of kernel 2 handles 2 rows

    compute_M_kernel<<<1, 64, 0, stream>>>(psi_r, psi_i, A_r, A_i, M);

    const int threads = 256;
    int blocks = (T2 + threads - 1) / threads;
    if (blocks > 2048) blocks = 2048;  // grid-stride the rest (Guideline 11)
    apply_M_kernel<<<blocks, threads, 0, stream>>>(x, M, out, T2);
}

// Round 2
// 34.343 us; speedup vs baseline: 1.1633x; 1.1633x over previous
//
#include <hip/hip_runtime.h>

// Problem constants (from reference)
constexpr int NC = 2;   // N_CLASSES
constexpr int NF = 10;  // N_FEATURES
constexpr int PD = 10;  // PSI_DIM

constexpr int THREADS = 256;
constexpr int F4_PER_THREAD = 5;                  // 2 rows = 20 floats = 5 float4
constexpr int TILE_F4 = THREADS * F4_PER_THREAD;  // 1280 float4
constexpr int TILE_FLOATS = TILE_F4 * 4;          // 5120 floats = 20480 B

// Single fused kernel:
//   Phase 0: 200 threads cooperatively compute M_r[k][a] (i-partials in LDS, reduce).
//            M_r[k,a] = sum_{i,j} (pr_i*Ar[k,i,j,a] - pi_i*Ai[k,i,j,a]) * (pr_j - pi_j)
//            (x_imag == 0 in the reference, so M_i never matters.)
//   Phase 1: grid-stride over 512-row tiles. Stage x via global_load_lds width=16
//            (perfectly coalesced HBM reads, linear LDS dest), then each thread
//            reads its 2 rows (80 B contiguous) from LDS and writes one float4.
__global__ __launch_bounds__(THREADS) void fused_complexnet_kernel(
        const float* __restrict__ x,
        const float* __restrict__ psi_r,
        const float* __restrict__ psi_i,
        const float* __restrict__ A_r,
        const float* __restrict__ A_i,
        float* __restrict__ out,
        int T2, long totalF4) {
    __shared__ float Msh[NC * NF];
    __shared__ float part[NC * NF * PD];   // 200 i-partials
    __shared__ float tile[TILE_FLOATS];    // 20480 B staging buffer

    const int t = threadIdx.x;

    // ---- Phase 0: M_r ----
    if (t < NC * NF * PD) {
        int k = t / (NF * PD);
        int rem = t - k * (NF * PD);
        int a = rem / PD;
        int i = rem - a * PD;
        float pri = psi_r[i], pii = psi_i[i];
        float acc = 0.f;
#pragma unroll
        for (int j = 0; j < PD; ++j) {
            float dj = psi_r[j] - psi_i[j];
            int idx = ((k * PD + i) * PD + j) * NF + a;
            acc = fmaf(pri * A_r[idx] - pii * A_i[idx], dj, acc);
        }
        part[t] = acc;
    }
    __syncthreads();
    if (t < NC * NF) {
        int k = t / NF, a = t - k * NF;
        float s = 0.f;
#pragma unroll
        for (int i = 0; i < PD; ++i) s += part[(k * NF + a) * PD + i];
        Msh[t] = s;
    }
    __syncthreads();

    float m0[NF], m1[NF];
#pragma unroll
    for (int a = 0; a < NF; ++a) {
        m0[a] = Msh[a];
        m1[a] = Msh[NF + a];
    }

    const float4* x4 = reinterpret_cast<const float4*>(x);
    float4* out4 = reinterpret_cast<float4*>(out);
    const int nTiles = (T2 + THREADS - 1) / THREADS;
    // LDS float offset of this wave's first lane within each q-chunk
    const int waveBaseF = (t & ~63) * 4;

    for (int tileIdx = blockIdx.x; tileIdx < nTiles; tileIdx += (int)gridDim.x) {
        const long base4 = (long)tileIdx * TILE_F4;
        // ---- stage: 5 chunks of 256 float4, coalesced, direct to LDS ----
#pragma unroll
        for (int q = 0; q < F4_PER_THREAD; ++q) {
            long g4 = base4 + (long)q * THREADS + t;
            if (g4 >= totalF4) g4 = totalF4 - 1;  // clamp: duplicate reads, never stored
            const float* ldsdst = &tile[q * (THREADS * 4) + waveBaseF];
            __builtin_amdgcn_global_load_lds(
                (const __attribute__((address_space(1))) void*)(x4 + g4),
                (__attribute__((address_space(3))) void*)ldsdst,
                16, 0, 0);
        }
        __syncthreads();  // drains vmcnt(0) -> staged data visible

        // ---- compute: 2 rows per thread from LDS ----
        const int rp = tileIdx * THREADS + t;  // row-pair index
        if (rp < T2) {
            const float4* lp = reinterpret_cast<const float4*>(&tile[t * 20]);
            float4 v0 = lp[0], v1 = lp[1], v2 = lp[2], v3 = lp[3], v4 = lp[4];
            float r0[NF] = {v0.x, v0.y, v0.z, v0.w, v1.x, v1.y, v1.z, v1.w, v2.x, v2.y};
            float r1[NF] = {v2.z, v2.w, v3.x, v3.y, v3.z, v3.w, v4.x, v4.y, v4.z, v4.w};
            float4 o = {0.f, 0.f, 0.f, 0.f};
#pragma unroll
            for (int a = 0; a < NF; ++a) {
                o.x = fmaf(r0[a], m0[a], o.x);
                o.y = fmaf(r0[a], m1[a], o.y);
                o.z = fmaf(r1[a], m0[a], o.z);
                o.w = fmaf(r1[a], m1[a], o.w);
            }
            out4[rp] = o;
        }
        __syncthreads();  // protect tile[] before next stage
    }
}

extern "C" void kernel_launch(void* const* d_in, const int* in_sizes, int n_in,
                              void* d_out, int out_size, void* d_ws, size_t ws_size,
                              hipStream_t stream) {
    const float* x     = (const float*)d_in[0];
    const float* psi_r = (const float*)d_in[1];
    const float* psi_i = (const float*)d_in[2];
    const float* A_r   = (const float*)d_in[3];
    const float* A_i   = (const float*)d_in[4];
    float* out = (float*)d_out;

    const int T = in_sizes[0] / NF;        // 4,000,000 rows
    const int T2 = T / 2;                  // row-pairs
    const long totalF4 = (long)in_sizes[0] / 4;

    const int nTiles = (T2 + THREADS - 1) / THREADS;
    int blocks = nTiles < 1792 ? nTiles : 1792;  // 7 blocks/CU (LDS-limited) x 256 CU

    fused_complexnet_kernel<<<blocks, THREADS, 0, stream>>>(
        x, psi_r, psi_i, A_r, A_i, out, T2, totalF4);
}